// Round 8
// baseline (105.059 us; speedup 1.0000x reference)
//
#include <hip/hip_runtime.h>
#include <hip/hip_fp16.h>
#include <cstdint>
#include <cstddef>

typedef _Float16 f16;
typedef __attribute__((ext_vector_type(8))) _Float16 f16x8;
typedef __attribute__((ext_vector_type(4))) _Float16 f16x4;
typedef __attribute__((ext_vector_type(8))) short s16x8;   // 8 x bf16
typedef __attribute__((ext_vector_type(4))) float f32x4;

#define S_LEN 4096
#define D_DIM 1024
#define SOFT_C 160.0f

__device__ __forceinline__ void gld_lds16(const void* g, void* l) {
    auto gp = reinterpret_cast<const unsigned int __attribute__((address_space(1)))*>(
        reinterpret_cast<uintptr_t>(g));
    auto lp = reinterpret_cast<unsigned int __attribute__((address_space(3)))*>(
        reinterpret_cast<uintptr_t>(l));
    __builtin_amdgcn_global_load_lds(gp, lp, 16, 0, 0);
}

// float -> bf16 (round-to-nearest-even)
__device__ __forceinline__ unsigned short f2bf(float x) {
    unsigned u = __builtin_bit_cast(unsigned, x);
    u += 0x7FFFu + ((u >> 16) & 1u);
    return (unsigned short)(u >> 16);
}

#define BAR()    __builtin_amdgcn_s_barrier()
#define VM(n)    asm volatile("s_waitcnt vmcnt(" #n ")" ::: "memory")

// ---------------------------------------------------------------------------
// Fused prep: convert Q,K f32->f16 (blocks 0..8191); transpose V -> bf16
// ---------------------------------------------------------------------------
__global__ __launch_bounds__(256)
void prep(const float* __restrict__ Q, const float* __restrict__ K,
          const float* __restrict__ V,
          f16* __restrict__ Qh, f16* __restrict__ Kh, unsigned short* __restrict__ Vt)
{
    const int b = blockIdx.x;
    if (b < 8192) {
        int idx = b * 256 + threadIdx.x;
        const int NQ4 = S_LEN * D_DIM / 4;
        const float* src;
        f16* dst;
        int i = idx;
        if (i < NQ4) { src = Q; dst = Qh; }
        else         { src = K; dst = Kh; i -= NQ4; }
        float4 v = ((const float4*)src)[i];
        f16x4 h = {(_Float16)v.x, (_Float16)v.y, (_Float16)v.z, (_Float16)v.w};
        *(f16x4*)&dst[(size_t)i * 4] = h;
    } else {
        __shared__ float tile[32][33];
        const int bb = b - 8192;
        const int bx = bb & 31;
        const int by = bb >> 5;
        const int tx = threadIdx.x & 31;
        const int ty = threadIdx.x >> 5;
#pragma unroll
        for (int j = 0; j < 4; ++j)
            tile[ty + j * 8][tx] = V[(size_t)(by * 32 + ty + j * 8) * D_DIM + bx * 32 + tx];
        __syncthreads();
#pragma unroll
        for (int j = 0; j < 4; ++j)
            Vt[(size_t)(bx * 32 + ty + j * 8) * S_LEN + by * 32 + tx] =
                f2bf(tile[tx][ty + j * 8]);
    }
}

// ===========================================================================
// GEMM1: E = exp(Qh*Kh^T - C) -> bf16 + partial row sums.
// 256x128 tile, 4 waves (2x2), BK=32, 3-slot LDS ring (72 KiB -> 2 blocks/CU),
// grid 512 (16 M x 32 N tiles). One barrier / K-tile; counted VM(6).
// ===========================================================================
__global__ __launch_bounds__(256, 2)
void gemm_exp(const f16* __restrict__ A, const f16* __restrict__ B,
              unsigned short* __restrict__ C, float* __restrict__ psum)
{
    __shared__ f16 sA[3][256 * 32];   // 16 KB / slot
    __shared__ f16 sB[3][128 * 32];   // 8 KB / slot

    const int tid = threadIdx.x;
    const int w = tid >> 6;           // 0..3
    const int l = tid & 63;
    const int lr = l & 15;
    const int lk = l >> 4;
    const int wm = w >> 1;            // 0..1 (M half: 128 rows)
    const int wn = w & 1;             // 0..1 (N half: 64 cols)

    const int cpx = gridDim.x >> 3;   // 64
    const int bid = blockIdx.x;
    const int swz = (bid & 7) * cpx + (bid >> 3);
    const int tm = (swz >> 5) * 256;  // 16 M-tiles
    const int tn = (swz & 31) * 128;  // 32 N-tiles
    const int NT = 32;                // K=1024 / 32

    int offA[8], offB[4];
#pragma unroll
    for (int mi = 0; mi < 8; ++mi) {
        const int ra = wm * 128 + mi * 16 + lr;
        offA[mi] = ra * 32 + (lk ^ ((ra >> 1) & 3)) * 8;
    }
#pragma unroll
    for (int ni = 0; ni < 4; ++ni) {
        const int rb = wn * 64 + ni * 16 + lr;
        offB[ni] = rb * 32 + (lk ^ ((rb >> 1) & 3)) * 8;
    }

    // stage tile t into slot: A 4 rounds, B 2 rounds (16B/thread/round)
    auto stage = [&](int slot, int t) {
        const int kt = t << 5;
#pragma unroll
        for (int r = 0; r < 4; ++r) {
            const int sbase = r * 256 + (w << 6);
            const int s = sbase + l;
            const int row = s >> 2;
            const int pos = s & 3;
            const int kb = pos ^ ((row >> 1) & 3);
            gld_lds16(A + (size_t)(tm + row) * D_DIM + kt + kb * 8, &sA[slot][sbase * 8]);
        }
#pragma unroll
        for (int r = 0; r < 2; ++r) {
            const int sbase = r * 256 + (w << 6);
            const int s = sbase + l;
            const int row = s >> 2;
            const int pos = s & 3;
            const int kb = pos ^ ((row >> 1) & 3);
            gld_lds16(B + (size_t)(tn + row) * D_DIM + kt + kb * 8, &sB[slot][sbase * 8]);
        }
    };

    f32x4 acc[8][4] = {};

    stage(0, 0);
    stage(1, 1);
    VM(6);        // tile 0 landed (tile 1's 6 loads remain in flight)
    BAR();

    int sl = 0;
    for (int t = 0; t < NT; ++t) {
        f16x8 af[8], bf[4];
#pragma unroll
        for (int i = 0; i < 8; ++i) af[i] = *(const f16x8*)(&sA[sl][0] + offA[i]);
#pragma unroll
        for (int i = 0; i < 4; ++i) bf[i] = *(const f16x8*)(&sB[sl][0] + offB[i]);

        if (t + 2 < NT) {
            const int s2 = (sl + 2 >= 3) ? sl - 1 : sl + 2;
            stage(s2, t + 2);
        }

        __builtin_amdgcn_s_setprio(1);
#pragma unroll
        for (int mi = 0; mi < 8; ++mi)
#pragma unroll
            for (int ni = 0; ni < 4; ++ni)
                acc[mi][ni] = __builtin_amdgcn_mfma_f32_16x16x32_f16(
                    af[mi], bf[ni], acc[mi][ni], 0, 0, 0);
        __builtin_amdgcn_s_setprio(0);

        if (t + 2 < NT)      { VM(6); }   // drain tile t+1; keep t+2 in flight
        else if (t + 1 < NT) { VM(0); }   // tail: drain last tile
        BAR();
        sl = (sl == 2) ? 0 : sl + 1;
    }

    // ---- epilogue: E = exp(s - C) -> bf16 store + partial row sums ----
    float rs[8][4];
#pragma unroll
    for (int mi = 0; mi < 8; ++mi)
#pragma unroll
        for (int j = 0; j < 4; ++j) rs[mi][j] = 0.f;

#pragma unroll
    for (int mi = 0; mi < 8; ++mi) {
        const int r0 = tm + wm * 128 + mi * 16 + (l >> 4) * 4;
#pragma unroll
        for (int ni = 0; ni < 4; ++ni) {
            const int c0 = tn + wn * 64 + ni * 16 + lr;
#pragma unroll
            for (int j = 0; j < 4; ++j) {
                float e = __expf(acc[mi][ni][j] - SOFT_C);
                C[(size_t)(r0 + j) * S_LEN + c0] = f2bf(e);
                rs[mi][j] += e;
            }
        }
    }
    // reduce over 16 lanes (lr) holding different columns of same rows
#pragma unroll
    for (int mi = 0; mi < 8; ++mi)
#pragma unroll
        for (int j = 0; j < 4; ++j)
#pragma unroll
            for (int m = 1; m < 16; m <<= 1)
                rs[mi][j] += __shfl_xor(rs[mi][j], m, 64);

    float* lsum = (float*)&sA[0][0];   // [2 wn][256 rows]
    __syncthreads();
    if (lr == 0) {
#pragma unroll
        for (int mi = 0; mi < 8; ++mi)
#pragma unroll
            for (int j = 0; j < 4; ++j)
                lsum[wn * 256 + wm * 128 + mi * 16 + (l >> 4) * 4 + j] = rs[mi][j];
    }
    __syncthreads();
    if (tid < 256) {
        float s = lsum[tid] + lsum[256 + tid];
        psum[(size_t)(tn >> 7) * S_LEN + tm + tid] = s;
    }
}

// ---------------------------------------------------------------------------
// Row sums -> reciprocal (32 N-tile partials)
// ---------------------------------------------------------------------------
__global__ __launch_bounds__(256)
void sumrows(const float* __restrict__ ps, float* __restrict__ invR)
{
    const int r = blockIdx.x * 256 + threadIdx.x;
    float s = 0.f;
#pragma unroll
    for (int j = 0; j < 32; ++j) s += ps[(size_t)j * S_LEN + r];
    invR[r] = 1.0f / s;
}

// ===========================================================================
// GEMM2: partial(bf16) = E x Vt^T (un-normalized), 256x128 tile, 4 waves,
// BK=32, 3-slot ring, split-K=4, grid 512 (16 M x 8 N x 4 splits).
// ===========================================================================
__global__ __launch_bounds__(256, 2)
void gemm_bt(const unsigned short* __restrict__ A, const unsigned short* __restrict__ B,
             unsigned short* __restrict__ P)
{
    __shared__ unsigned short sA[3][256 * 32];
    __shared__ unsigned short sB[3][128 * 32];

    const int tid = threadIdx.x;
    const int w = tid >> 6;
    const int l = tid & 63;
    const int lr = l & 15;
    const int lk = l >> 4;
    const int wm = w >> 1;
    const int wn = w & 1;

    const int cpx = gridDim.x >> 3;
    const int bid = blockIdx.x;
    const int swz = (bid & 7) * cpx + (bid >> 3);
    const int split = swz & 3;
    const int tidx = swz >> 2;        // 0..127
    const int tm = (tidx >> 3) * 256; // 16 M-tiles
    const int tn = (tidx & 7) * 128;  // 8 N-tiles
    const int koff = split * 1024;
    unsigned short* Cp = P + (size_t)split * ((size_t)S_LEN * D_DIM);
    const int NT = 32;                // 1024 / 32

    int offA[8], offB[4];
#pragma unroll
    for (int mi = 0; mi < 8; ++mi) {
        const int ra = wm * 128 + mi * 16 + lr;
        offA[mi] = ra * 32 + (lk ^ ((ra >> 1) & 3)) * 8;
    }
#pragma unroll
    for (int ni = 0; ni < 4; ++ni) {
        const int rb = wn * 64 + ni * 16 + lr;
        offB[ni] = rb * 32 + (lk ^ ((rb >> 1) & 3)) * 8;
    }

    auto stage = [&](int slot, int t) {
        const int kt = koff + (t << 5);
#pragma unroll
        for (int r = 0; r < 4; ++r) {
            const int sbase = r * 256 + (w << 6);
            const int s = sbase + l;
            const int row = s >> 2;
            const int pos = s & 3;
            const int kb = pos ^ ((row >> 1) & 3);
            gld_lds16(A + (size_t)(tm + row) * S_LEN + kt + kb * 8, &sA[slot][sbase * 8]);
        }
#pragma unroll
        for (int r = 0; r < 2; ++r) {
            const int sbase = r * 256 + (w << 6);
            const int s = sbase + l;
            const int row = s >> 2;
            const int pos = s & 3;
            const int kb = pos ^ ((row >> 1) & 3);
            gld_lds16(B + (size_t)(tn + row) * S_LEN + kt + kb * 8, &sB[slot][sbase * 8]);
        }
    };

    f32x4 acc[8][4] = {};

    stage(0, 0);
    stage(1, 1);
    VM(6);
    BAR();

    int sl = 0;
    for (int t = 0; t < NT; ++t) {
        s16x8 af[8], bf[4];
#pragma unroll
        for (int i = 0; i < 8; ++i) af[i] = *(const s16x8*)(&sA[sl][0] + offA[i]);
#pragma unroll
        for (int i = 0; i < 4; ++i) bf[i] = *(const s16x8*)(&sB[sl][0] + offB[i]);

        if (t + 2 < NT) {
            const int s2 = (sl + 2 >= 3) ? sl - 1 : sl + 2;
            stage(s2, t + 2);
        }

        __builtin_amdgcn_s_setprio(1);
#pragma unroll
        for (int mi = 0; mi < 8; ++mi)
#pragma unroll
            for (int ni = 0; ni < 4; ++ni)
                acc[mi][ni] = __builtin_amdgcn_mfma_f32_16x16x32_bf16(
                    af[mi], bf[ni], acc[mi][ni], 0, 0, 0);
        __builtin_amdgcn_s_setprio(0);

        if (t + 2 < NT)      { VM(6); }
        else if (t + 1 < NT) { VM(0); }
        BAR();
        sl = (sl == 2) ? 0 : sl + 1;
    }

    // epilogue: bf16 partial store
#pragma unroll
    for (int mi = 0; mi < 8; ++mi) {
        const int r0 = tm + wm * 128 + mi * 16 + (l >> 4) * 4;
#pragma unroll
        for (int ni = 0; ni < 4; ++ni) {
            const int c0 = tn + wn * 64 + ni * 16 + lr;
#pragma unroll
            for (int j = 0; j < 4; ++j)
                Cp[(size_t)(r0 + j) * D_DIM + c0] = f2bf(acc[mi][ni][j]);
        }
    }
}

// ---------------------------------------------------------------------------
// Combine 4 bf16 split-K partials, normalize by invR -> O f32
// ---------------------------------------------------------------------------
__global__ __launch_bounds__(256)
void combine4(const unsigned short* __restrict__ P, const float* __restrict__ invR,
              float* __restrict__ O)
{
    const size_t g = (size_t)blockIdx.x * 256 + threadIdx.x;
    const size_t n = (size_t)S_LEN * D_DIM;
    const int row = (int)(g >> 8);
    const float s = invR[row];
    float4 r = {0.f, 0.f, 0.f, 0.f};
#pragma unroll
    for (int sp = 0; sp < 4; ++sp) {
        uint2 u = ((const uint2*)(P + (size_t)sp * n))[g];
        r.x += __builtin_bit_cast(float, (u.x & 0xFFFFu) << 16);
        r.y += __builtin_bit_cast(float, u.x & 0xFFFF0000u);
        r.z += __builtin_bit_cast(float, (u.y & 0xFFFFu) << 16);
        r.w += __builtin_bit_cast(float, u.y & 0xFFFF0000u);
    }
    r.x *= s; r.y *= s; r.z *= s; r.w *= s;
    ((float4*)O)[g] = r;
}

// ---------------------------------------------------------------------------
// Fallback: naive 2-pass attention
// ---------------------------------------------------------------------------
__global__ __launch_bounds__(256)
void attn_naive(const float* __restrict__ Q, const float* __restrict__ K,
                const float* __restrict__ V, float* __restrict__ O)
{
    const int r = blockIdx.x;
    const int t = threadIdx.x;
    __shared__ float red[4];
    float q[4];
#pragma unroll
    for (int i = 0; i < 4; ++i) q[i] = Q[(size_t)r * D_DIM + t + i * 256];

    float m = -1e30f;
    for (int j = 0; j < S_LEN; ++j) {
        float p = 0.f;
#pragma unroll
        for (int i = 0; i < 4; ++i) p += q[i] * K[(size_t)j * D_DIM + t + i * 256];
#pragma unroll
        for (int off = 32; off > 0; off >>= 1) p += __shfl_xor(p, off, 64);
        if ((t & 63) == 0) red[t >> 6] = p;
        __syncthreads();
        float s = (red[0] + red[1]) + (red[2] + red[3]);
        __syncthreads();
        m = fmaxf(m, s);
    }
    float acc[4] = {0.f, 0.f, 0.f, 0.f};
    float lsum = 0.f;
    for (int j = 0; j < S_LEN; ++j) {
        float p = 0.f;
#pragma unroll
        for (int i = 0; i < 4; ++i) p += q[i] * K[(size_t)j * D_DIM + t + i * 256];
#pragma unroll
        for (int off = 32; off > 0; off >>= 1) p += __shfl_xor(p, off, 64);
        if ((t & 63) == 0) red[t >> 6] = p;
        __syncthreads();
        float s = (red[0] + red[1]) + (red[2] + red[3]);
        __syncthreads();
        float e = __expf(s - m);
        lsum += e;
#pragma unroll
        for (int i = 0; i < 4; ++i) acc[i] += e * V[(size_t)j * D_DIM + t + i * 256];
    }
    const float inv = 1.f / lsum;
#pragma unroll
    for (int i = 0; i < 4; ++i) O[(size_t)r * D_DIM + t + i * 256] = acc[i] * inv;
}

// ---------------------------------------------------------------------------
extern "C" void kernel_launch(void* const* d_in, const int* in_sizes, int n_in,
                              void* d_out, int out_size, void* d_ws, size_t ws_size,
                              hipStream_t stream)
{
    const float* Q = (const float*)d_in[0];
    const float* K = (const float*)d_in[1];
    const float* V = (const float*)d_in[2];
    float* O = (float*)d_out;

    const size_t MB = 1024ull * 1024ull;
    const size_t QH_OFF = 0;
    const size_t KH_OFF = 8 * MB;
    const size_t VT_OFF = 16 * MB;
    const size_t E_OFF  = 24 * MB;
    const size_t PS_OFF = 56 * MB;                 // [32][4096] f32 = 512 KB
    const size_t IV_OFF = 56 * MB + 512 * 1024;
    const size_t P_OFF  = 57 * MB;
    const size_t NEED   = 90 * MB;

    if (ws_size < NEED) {
        attn_naive<<<S_LEN, 256, 0, stream>>>(Q, K, V, O);
        return;
    }

    char* ws = (char*)d_ws;
    f16*            Qh  = (f16*)(ws + QH_OFF);
    f16*            Kh  = (f16*)(ws + KH_OFF);
    unsigned short* Vt  = (unsigned short*)(ws + VT_OFF);
    unsigned short* E   = (unsigned short*)(ws + E_OFF);
    float*          ps  = (float*)(ws + PS_OFF);
    float*          inv = (float*)(ws + IV_OFF);
    unsigned short* P   = (unsigned short*)(ws + P_OFF);

    prep<<<8192 + 4096, 256, 0, stream>>>(Q, K, V, Qh, Kh, Vt);

    // E = exp(Qh*Kh^T - C) bf16 + partial row sums (512 blocks, 2/CU)
    gemm_exp<<<512, 256, 0, stream>>>(Qh, Kh, E, ps);

    sumrows<<<16, 256, 0, stream>>>(ps, inv);

    // partials = E x Vt^T (un-normalized), split-K=4 (512 blocks, 2/CU)
    gemm_bt<<<512, 256, 0, stream>>>(E, Vt, P);

    // O = invR * sum(partials)
    combine4<<<S_LEN * D_DIM / 4 / 256, 256, 0, stream>>>(P, inv, O);
}

// Round 9
// 101.190 us; speedup vs baseline: 1.0382x; 1.0382x over previous
//
#include <hip/hip_runtime.h>
#include <hip/hip_fp16.h>
#include <cstdint>
#include <cstddef>

typedef _Float16 f16;
typedef __attribute__((ext_vector_type(8))) _Float16 f16x8;
typedef __attribute__((ext_vector_type(4))) _Float16 f16x4;
typedef __attribute__((ext_vector_type(8))) short s16x8;   // 8 x bf16
typedef __attribute__((ext_vector_type(4))) float f32x4;

#define S_LEN 4096
#define D_DIM 1024
#define SOFT_C 160.0f

__device__ __forceinline__ void gld_lds16(const void* g, void* l) {
    auto gp = reinterpret_cast<const unsigned int __attribute__((address_space(1)))*>(
        reinterpret_cast<uintptr_t>(g));
    auto lp = reinterpret_cast<unsigned int __attribute__((address_space(3)))*>(
        reinterpret_cast<uintptr_t>(l));
    __builtin_amdgcn_global_load_lds(gp, lp, 16, 0, 0);
}

// float -> bf16 (round-to-nearest-even)
__device__ __forceinline__ unsigned short f2bf(float x) {
    unsigned u = __builtin_bit_cast(unsigned, x);
    u += 0x7FFFu + ((u >> 16) & 1u);
    return (unsigned short)(u >> 16);
}

#define SCHED0() __builtin_amdgcn_sched_barrier(0)
#define BAR()    __builtin_amdgcn_s_barrier()
#define LGKM0()  asm volatile("s_waitcnt lgkmcnt(0)" ::: "memory")
#define VM(n)    asm volatile("s_waitcnt vmcnt(" #n ")" ::: "memory")

// ---------------------------------------------------------------------------
// Fused prep: convert Q,K f32->f16 (blocks 0..8191); transpose V -> bf16
// ---------------------------------------------------------------------------
__global__ __launch_bounds__(256)
void prep(const float* __restrict__ Q, const float* __restrict__ K,
          const float* __restrict__ V,
          f16* __restrict__ Qh, f16* __restrict__ Kh, unsigned short* __restrict__ Vt)
{
    const int b = blockIdx.x;
    if (b < 8192) {
        int idx = b * 256 + threadIdx.x;
        const int NQ4 = S_LEN * D_DIM / 4;
        const float* src;
        f16* dst;
        int i = idx;
        if (i < NQ4) { src = Q; dst = Qh; }
        else         { src = K; dst = Kh; i -= NQ4; }
        float4 v = ((const float4*)src)[i];
        f16x4 h = {(_Float16)v.x, (_Float16)v.y, (_Float16)v.z, (_Float16)v.w};
        *(f16x4*)&dst[(size_t)i * 4] = h;
    } else {
        __shared__ float tile[32][33];
        const int bb = b - 8192;
        const int bx = bb & 31;
        const int by = bb >> 5;
        const int tx = threadIdx.x & 31;
        const int ty = threadIdx.x >> 5;
#pragma unroll
        for (int j = 0; j < 4; ++j)
            tile[ty + j * 8][tx] = V[(size_t)(by * 32 + ty + j * 8) * D_DIM + bx * 32 + tx];
        __syncthreads();
#pragma unroll
        for (int j = 0; j < 4; ++j)
            Vt[(size_t)(bx * 32 + ty + j * 8) * S_LEN + by * 32 + tx] =
                f2bf(tile[tx][ty + j * 8]);
    }
}

// ===========================================================================
// 8-phase-template GEMM core geometry (both GEMMs):
// 256x256 tile, 512 thr (8 waves 2Mx4N, wave-out 128x64), BK=64 as 2 K-halves,
// ring of 4 half-slots/operand (2-tile double buffer, 128 KiB LDS).
// Per K-tile: 4 phases {reads(8/4/8/4 via base+imm-offset), stage 1 half
// (2 gld_lds), BAR, lgkm0, setprio 16-MFMA}, VM(6) once/tile at phi3.
// Stage plan (tile u): phi0: A(u+1,h1); phi1: B(u+2,h0); phi2: A(u+2,h0);
// phi3: B(u+2,h1). Slot-race + vmcnt-lead invariants hand-verified.
// ===========================================================================

// ---------------------------------------------------------------------------
// GEMM1: E = exp(Qh*Kh^T - C) -> bf16 + partial row sums.  f16 MFMA.
// ---------------------------------------------------------------------------
__global__ __launch_bounds__(512, 2)
void gemm_exp(const f16* __restrict__ A, const f16* __restrict__ B,
              unsigned short* __restrict__ C, float* __restrict__ psum,
              int lda, int ldb, int ldc, int K, int tilesN)
{
    __shared__ f16 sA[4][256 * 32];   // 4 half-slots x 16 KB
    __shared__ f16 sB[4][256 * 32];

    const int tid = threadIdx.x;
    const int w = tid >> 6;
    const int l = tid & 63;
    const int lr = l & 15;
    const int lk = l >> 4;
    const int wm = w >> 2;            // 0..1
    const int wn = w & 3;             // 0..3

    const int cpx = gridDim.x >> 3;
    const int bid = blockIdx.x;
    const int swz = (bid & 7) * cpx + (bid >> 3);
    const int tm = (swz / tilesN) * 256;
    const int tn = (swz % tilesN) * 256;
    const int NT = K >> 6;            // K-tiles of 64 (=16)

    // single per-thread base byte-offsets; frag i at +i*1024 bytes
    const int swzk = lk ^ ((lr >> 1) & 3);
    const int offA0b = ((wm * 128 + lr) * 32 + swzk * 8) * 2;
    const int offB0b = ((wn * 64 + lr) * 32 + swzk * 8) * 2;

    auto stgA = [&](int t, int h) {
        const int slot = (2 * t + h) & 3;
        const int gk = (t << 6) + (h << 5);
#pragma unroll
        for (int r = 0; r < 2; ++r) {
            const int sbase = r * 512 + (w << 6);
            const int s = sbase + l;
            const int row = s >> 2;
            const int kb = (s & 3) ^ ((row >> 1) & 3);
            gld_lds16(A + (size_t)(tm + row) * lda + gk + kb * 8, &sA[slot][sbase * 8]);
        }
    };
    auto stgB = [&](int t, int h) {
        const int slot = (2 * t + h) & 3;
        const int gk = (t << 6) + (h << 5);
#pragma unroll
        for (int r = 0; r < 2; ++r) {
            const int sbase = r * 512 + (w << 6);
            const int s = sbase + l;
            const int row = s >> 2;
            const int kb = (s & 3) ^ ((row >> 1) & 3);
            gld_lds16(B + (size_t)(tn + row) * ldb + gk + kb * 8, &sB[slot][sbase * 8]);
        }
    };

    f32x4 acc[8][4] = {};

    // prologue: tile0 all 4 halves + A(1,h0),B(1,h0),B(1,h1).  A(1,h1) at u0.phi0
    stgA(0, 0); stgB(0, 0); stgA(0, 1); stgB(0, 1);
    stgA(1, 0); stgB(1, 0); stgB(1, 1);
    VM(6);                       // tile 0's 8 loads drained
    BAR();

    for (int u = 0; u < NT; ++u) {
        const char* a0 = (const char*)&sA[(2 * u) & 3][0];
        const char* a1 = (const char*)&sA[(2 * u + 1) & 3][0];
        const char* b0 = (const char*)&sB[(2 * u) & 3][0];
        const char* b1 = (const char*)&sB[(2 * u + 1) & 3][0];
        f16x8 af[4], bf0[4], bf1[4];

        // ---- phi0: m0-3 x k-half0 ----
        SCHED0();
#pragma unroll
        for (int i = 0; i < 4; ++i) af[i]  = *(const f16x8*)(a0 + offA0b + i * 1024);
#pragma unroll
        for (int i = 0; i < 4; ++i) bf0[i] = *(const f16x8*)(b0 + offB0b + i * 1024);
        if (u + 1 < NT) stgA(u + 1, 1);
        BAR(); LGKM0(); SCHED0();
        __builtin_amdgcn_s_setprio(1);
#pragma unroll
        for (int mi = 0; mi < 4; ++mi)
#pragma unroll
            for (int ni = 0; ni < 4; ++ni)
                acc[mi][ni] = __builtin_amdgcn_mfma_f32_16x16x32_f16(
                    af[mi], bf0[ni], acc[mi][ni], 0, 0, 0);
        __builtin_amdgcn_s_setprio(0);
        BAR();

        // ---- phi1: m4-7 x k-half0 (bf0 held) ----
        SCHED0();
#pragma unroll
        for (int i = 0; i < 4; ++i) af[i] = *(const f16x8*)(a0 + offA0b + (4 + i) * 1024);
        if (u + 2 < NT) stgB(u + 2, 0);
        BAR(); LGKM0(); SCHED0();
        __builtin_amdgcn_s_setprio(1);
#pragma unroll
        for (int mi = 0; mi < 4; ++mi)
#pragma unroll
            for (int ni = 0; ni < 4; ++ni)
                acc[4 + mi][ni] = __builtin_amdgcn_mfma_f32_16x16x32_f16(
                    af[mi], bf0[ni], acc[4 + mi][ni], 0, 0, 0);
        __builtin_amdgcn_s_setprio(0);
        BAR();

        // ---- phi2: m0-3 x k-half1 ----
        SCHED0();
#pragma unroll
        for (int i = 0; i < 4; ++i) af[i]  = *(const f16x8*)(a1 + offA0b + i * 1024);
#pragma unroll
        for (int i = 0; i < 4; ++i) bf1[i] = *(const f16x8*)(b1 + offB0b + i * 1024);
        if (u + 2 < NT) stgA(u + 2, 0);
        BAR(); LGKM0(); SCHED0();
        __builtin_amdgcn_s_setprio(1);
#pragma unroll
        for (int mi = 0; mi < 4; ++mi)
#pragma unroll
            for (int ni = 0; ni < 4; ++ni)
                acc[mi][ni] = __builtin_amdgcn_mfma_f32_16x16x32_f16(
                    af[mi], bf1[ni], acc[mi][ni], 0, 0, 0);
        __builtin_amdgcn_s_setprio(0);
        BAR();

        // ---- phi3: m4-7 x k-half1 (bf1 held) ----
        SCHED0();
#pragma unroll
        for (int i = 0; i < 4; ++i) af[i] = *(const f16x8*)(a1 + offA0b + (4 + i) * 1024);
        if (u + 2 < NT) { stgB(u + 2, 1); VM(6); }
        else if (u + 1 < NT) { VM(0); }
        BAR(); LGKM0(); SCHED0();
        __builtin_amdgcn_s_setprio(1);
#pragma unroll
        for (int mi = 0; mi < 4; ++mi)
#pragma unroll
            for (int ni = 0; ni < 4; ++ni)
                acc[4 + mi][ni] = __builtin_amdgcn_mfma_f32_16x16x32_f16(
                    af[mi], bf1[ni], acc[4 + mi][ni], 0, 0, 0);
        __builtin_amdgcn_s_setprio(0);
        BAR();
    }

    // ---- epilogue: E = exp(s - C) -> bf16 store + partial row sums ----
    float rs[8][4];
#pragma unroll
    for (int mi = 0; mi < 8; ++mi)
#pragma unroll
        for (int j = 0; j < 4; ++j) rs[mi][j] = 0.f;

#pragma unroll
    for (int mi = 0; mi < 8; ++mi) {
        const int r0 = tm + wm * 128 + mi * 16 + (l >> 4) * 4;
#pragma unroll
        for (int ni = 0; ni < 4; ++ni) {
            const int c0 = tn + wn * 64 + ni * 16 + lr;
#pragma unroll
            for (int j = 0; j < 4; ++j) {
                float e = __expf(acc[mi][ni][j] - SOFT_C);
                C[(size_t)(r0 + j) * ldc + c0] = f2bf(e);
                rs[mi][j] += e;
            }
        }
    }
#pragma unroll
    for (int mi = 0; mi < 8; ++mi)
#pragma unroll
        for (int j = 0; j < 4; ++j)
#pragma unroll
            for (int m = 1; m < 16; m <<= 1)
                rs[mi][j] += __shfl_xor(rs[mi][j], m, 64);

    float* lsum = (float*)&sA[0][0];   // [4 wn][256 rows]
    __syncthreads();
    if (lr == 0) {
#pragma unroll
        for (int mi = 0; mi < 8; ++mi)
#pragma unroll
            for (int j = 0; j < 4; ++j)
                lsum[wn * 256 + wm * 128 + mi * 16 + (l >> 4) * 4 + j] = rs[mi][j];
    }
    __syncthreads();
    if (tid < 256) {
        float s = (lsum[tid] + lsum[256 + tid]) + (lsum[512 + tid] + lsum[768 + tid]);
        psum[(size_t)(tn >> 8) * S_LEN + tm + tid] = s;
    }
}

// ---------------------------------------------------------------------------
// Row sums -> reciprocal
// ---------------------------------------------------------------------------
__global__ __launch_bounds__(256)
void sumrows(const float* __restrict__ ps, float* __restrict__ invR)
{
    const int r = blockIdx.x * 256 + threadIdx.x;
    float s = 0.f;
#pragma unroll
    for (int j = 0; j < 16; ++j) s += ps[(size_t)j * S_LEN + r];
    invR[r] = 1.0f / s;
}

// ---------------------------------------------------------------------------
// GEMM2: partial(bf16) = E x Vt^T, split-K=4, same 8-phase core, bf16 MFMA.
// ---------------------------------------------------------------------------
__global__ __launch_bounds__(512, 2)
void gemm_bt(const unsigned short* __restrict__ A, const unsigned short* __restrict__ B,
             unsigned short* __restrict__ P)
{
    __shared__ unsigned short sA[4][256 * 32];
    __shared__ unsigned short sB[4][256 * 32];

    const int tid = threadIdx.x;
    const int w = tid >> 6;
    const int l = tid & 63;
    const int lr = l & 15;
    const int lk = l >> 4;
    const int wm = w >> 2;
    const int wn = w & 3;

    const int cpx = gridDim.x >> 3;
    const int bid = blockIdx.x;
    const int swz = (bid & 7) * cpx + (bid >> 3);
    const int split = swz & 3;
    const int tidx = swz >> 2;
    const int tm = (tidx >> 2) * 256;      // tilesN = 4
    const int tn = (tidx & 3) * 256;
    const int koff = split * 1024;
    unsigned short* Cp = P + (size_t)split * ((size_t)S_LEN * D_DIM);
    const int NT = 16;

    const int swzk = lk ^ ((lr >> 1) & 3);
    const int offA0b = ((wm * 128 + lr) * 32 + swzk * 8) * 2;
    const int offB0b = ((wn * 64 + lr) * 32 + swzk * 8) * 2;

    auto stgA = [&](int t, int h) {
        const int slot = (2 * t + h) & 3;
        const int gk = koff + (t << 6) + (h << 5);
#pragma unroll
        for (int r = 0; r < 2; ++r) {
            const int sbase = r * 512 + (w << 6);
            const int s = sbase + l;
            const int row = s >> 2;
            const int kb = (s & 3) ^ ((row >> 1) & 3);
            gld_lds16(A + (size_t)(tm + row) * S_LEN + gk + kb * 8, &sA[slot][sbase * 8]);
        }
    };
    auto stgB = [&](int t, int h) {
        const int slot = (2 * t + h) & 3;
        const int gk = koff + (t << 6) + (h << 5);
#pragma unroll
        for (int r = 0; r < 2; ++r) {
            const int sbase = r * 512 + (w << 6);
            const int s = sbase + l;
            const int row = s >> 2;
            const int kb = (s & 3) ^ ((row >> 1) & 3);
            gld_lds16(B + (size_t)(tn + row) * S_LEN + gk + kb * 8, &sB[slot][sbase * 8]);
        }
    };

    f32x4 acc[8][4] = {};

    stgA(0, 0); stgB(0, 0); stgA(0, 1); stgB(0, 1);
    stgA(1, 0); stgB(1, 0); stgB(1, 1);
    VM(6);
    BAR();

    for (int u = 0; u < NT; ++u) {
        const char* a0 = (const char*)&sA[(2 * u) & 3][0];
        const char* a1 = (const char*)&sA[(2 * u + 1) & 3][0];
        const char* b0 = (const char*)&sB[(2 * u) & 3][0];
        const char* b1 = (const char*)&sB[(2 * u + 1) & 3][0];
        s16x8 af[4], bf0[4], bf1[4];

        // ---- phi0 ----
        SCHED0();
#pragma unroll
        for (int i = 0; i < 4; ++i) af[i]  = *(const s16x8*)(a0 + offA0b + i * 1024);
#pragma unroll
        for (int i = 0; i < 4; ++i) bf0[i] = *(const s16x8*)(b0 + offB0b + i * 1024);
        if (u + 1 < NT) stgA(u + 1, 1);
        BAR(); LGKM0(); SCHED0();
        __builtin_amdgcn_s_setprio(1);
#pragma unroll
        for (int mi = 0; mi < 4; ++mi)
#pragma unroll
            for (int ni = 0; ni < 4; ++ni)
                acc[mi][ni] = __builtin_amdgcn_mfma_f32_16x16x32_bf16(
                    af[mi], bf0[ni], acc[mi][ni], 0, 0, 0);
        __builtin_amdgcn_s_setprio(0);
        BAR();

        // ---- phi1 ----
        SCHED0();
#pragma unroll
        for (int i = 0; i < 4; ++i) af[i] = *(const s16x8*)(a0 + offA0b + (4 + i) * 1024);
        if (u + 2 < NT) stgB(u + 2, 0);
        BAR(); LGKM0(); SCHED0();
        __builtin_amdgcn_s_setprio(1);
#pragma unroll
        for (int mi = 0; mi < 4; ++mi)
#pragma unroll
            for (int ni = 0; ni < 4; ++ni)
                acc[4 + mi][ni] = __builtin_amdgcn_mfma_f32_16x16x32_bf16(
                    af[mi], bf0[ni], acc[4 + mi][ni], 0, 0, 0);
        __builtin_amdgcn_s_setprio(0);
        BAR();

        // ---- phi2 ----
        SCHED0();
#pragma unroll
        for (int i = 0; i < 4; ++i) af[i]  = *(const s16x8*)(a1 + offA0b + i * 1024);
#pragma unroll
        for (int i = 0; i < 4; ++i) bf1[i] = *(const s16x8*)(b1 + offB0b + i * 1024);
        if (u + 2 < NT) stgA(u + 2, 0);
        BAR(); LGKM0(); SCHED0();
        __builtin_amdgcn_s_setprio(1);
#pragma unroll
        for (int mi = 0; mi < 4; ++mi)
#pragma unroll
            for (int ni = 0; ni < 4; ++ni)
                acc[mi][ni] = __builtin_amdgcn_mfma_f32_16x16x32_bf16(
                    af[mi], bf1[ni], acc[mi][ni], 0, 0, 0);
        __builtin_amdgcn_s_setprio(0);
        BAR();

        // ---- phi3 ----
        SCHED0();
#pragma unroll
        for (int i = 0; i < 4; ++i) af[i] = *(const s16x8*)(a1 + offA0b + (4 + i) * 1024);
        if (u + 2 < NT) { stgB(u + 2, 1); VM(6); }
        else if (u + 1 < NT) { VM(0); }
        BAR(); LGKM0(); SCHED0();
        __builtin_amdgcn_s_setprio(1);
#pragma unroll
        for (int mi = 0; mi < 4; ++mi)
#pragma unroll
            for (int ni = 0; ni < 4; ++ni)
                acc[4 + mi][ni] = __builtin_amdgcn_mfma_f32_16x16x32_bf16(
                    af[mi], bf1[ni], acc[4 + mi][ni], 0, 0, 0);
        __builtin_amdgcn_s_setprio(0);
        BAR();
    }

    // epilogue: bf16 partial store
#pragma unroll
    for (int mi = 0; mi < 8; ++mi) {
        const int r0 = tm + wm * 128 + mi * 16 + (l >> 4) * 4;
#pragma unroll
        for (int ni = 0; ni < 4; ++ni) {
            const int c0 = tn + wn * 64 + ni * 16 + lr;
#pragma unroll
            for (int j = 0; j < 4; ++j)
                Cp[(size_t)(r0 + j) * D_DIM + c0] = f2bf(acc[mi][ni][j]);
        }
    }
}

// ---------------------------------------------------------------------------
// Combine 4 bf16 split-K partials, normalize by invR -> O f32
// ---------------------------------------------------------------------------
__global__ __launch_bounds__(256)
void combine4(const unsigned short* __restrict__ P, const float* __restrict__ invR,
              float* __restrict__ O)
{
    const size_t g = (size_t)blockIdx.x * 256 + threadIdx.x;
    const size_t n = (size_t)S_LEN * D_DIM;
    const int row = (int)(g >> 8);
    const float s = invR[row];
    float4 r = {0.f, 0.f, 0.f, 0.f};
#pragma unroll
    for (int sp = 0; sp < 4; ++sp) {
        uint2 u = ((const uint2*)(P + (size_t)sp * n))[g];
        r.x += __builtin_bit_cast(float, (u.x & 0xFFFFu) << 16);
        r.y += __builtin_bit_cast(float, u.x & 0xFFFF0000u);
        r.z += __builtin_bit_cast(float, (u.y & 0xFFFFu) << 16);
        r.w += __builtin_bit_cast(float, u.y & 0xFFFF0000u);
    }
    r.x *= s; r.y *= s; r.z *= s; r.w *= s;
    ((float4*)O)[g] = r;
}

// ---------------------------------------------------------------------------
// Fallback: naive 2-pass attention
// ---------------------------------------------------------------------------
__global__ __launch_bounds__(256)
void attn_naive(const float* __restrict__ Q, const float* __restrict__ K,
                const float* __restrict__ V, float* __restrict__ O)
{
    const int r = blockIdx.x;
    const int t = threadIdx.x;
    __shared__ float red[4];
    float q[4];
#pragma unroll
    for (int i = 0; i < 4; ++i) q[i] = Q[(size_t)r * D_DIM + t + i * 256];

    float m = -1e30f;
    for (int j = 0; j < S_LEN; ++j) {
        float p = 0.f;
#pragma unroll
        for (int i = 0; i < 4; ++i) p += q[i] * K[(size_t)j * D_DIM + t + i * 256];
#pragma unroll
        for (int off = 32; off > 0; off >>= 1) p += __shfl_xor(p, off, 64);
        if ((t & 63) == 0) red[t >> 6] = p;
        __syncthreads();
        float s = (red[0] + red[1]) + (red[2] + red[3]);
        __syncthreads();
        m = fmaxf(m, s);
    }
    float acc[4] = {0.f, 0.f, 0.f, 0.f};
    float lsum = 0.f;
    for (int j = 0; j < S_LEN; ++j) {
        float p = 0.f;
#pragma unroll
        for (int i = 0; i < 4; ++i) p += q[i] * K[(size_t)j * D_DIM + t + i * 256];
#pragma unroll
        for (int off = 32; off > 0; off >>= 1) p += __shfl_xor(p, off, 64);
        if ((t & 63) == 0) red[t >> 6] = p;
        __syncthreads();
        float s = (red[0] + red[1]) + (red[2] + red[3]);
        __syncthreads();
        float e = __expf(s - m);
        lsum += e;
#pragma unroll
        for (int i = 0; i < 4; ++i) acc[i] += e * V[(size_t)j * D_DIM + t + i * 256];
    }
    const float inv = 1.f / lsum;
#pragma unroll
    for (int i = 0; i < 4; ++i) O[(size_t)r * D_DIM + t + i * 256] = acc[i] * inv;
}

// ---------------------------------------------------------------------------
extern "C" void kernel_launch(void* const* d_in, const int* in_sizes, int n_in,
                              void* d_out, int out_size, void* d_ws, size_t ws_size,
                              hipStream_t stream)
{
    const float* Q = (const float*)d_in[0];
    const float* K = (const float*)d_in[1];
    const float* V = (const float*)d_in[2];
    float* O = (float*)d_out;

    const size_t MB = 1024ull * 1024ull;
    const size_t QH_OFF = 0;
    const size_t KH_OFF = 8 * MB;
    const size_t VT_OFF = 16 * MB;
    const size_t E_OFF  = 24 * MB;
    const size_t PS_OFF = 56 * MB;
    const size_t IV_OFF = 56 * MB + 512 * 1024;
    const size_t P_OFF  = 57 * MB;
    const size_t NEED   = 90 * MB;

    if (ws_size < NEED) {
        attn_naive<<<S_LEN, 256, 0, stream>>>(Q, K, V, O);
        return;
    }

    char* ws = (char*)d_ws;
    f16*            Qh  = (f16*)(ws + QH_OFF);
    f16*            Kh  = (f16*)(ws + KH_OFF);
    unsigned short* Vt  = (unsigned short*)(ws + VT_OFF);
    unsigned short* E   = (unsigned short*)(ws + E_OFF);
    float*          ps  = (float*)(ws + PS_OFF);
    float*          inv = (float*)(ws + IV_OFF);
    unsigned short* P   = (unsigned short*)(ws + P_OFF);

    prep<<<8192 + 4096, 256, 0, stream>>>(Q, K, V, Qh, Kh, Vt);

    // E = exp(Qh*Kh^T - C) bf16 + partial row sums (256 blocks, 16x16 tiles)
    gemm_exp<<<256, 512, 0, stream>>>(Qh, Kh, E, ps, D_DIM, D_DIM, S_LEN,
                                      D_DIM, 16);

    sumrows<<<16, 256, 0, stream>>>(ps, inv);

    // partials = E x Vt^T (un-normalized), split-K=4
    gemm_bt<<<256, 512, 0, stream>>>(E, Vt, P);

    // O = invR * sum(partials)
    combine4<<<S_LEN * D_DIM / 4 / 256, 256, 0, stream>>>(P, inv, O);
}